// Round 2
// baseline (491.408 us; speedup 1.0000x reference)
//
#include <hip/hip_runtime.h>
#include <hip/hip_bf16.h>

typedef __hip_bfloat16 bf16;

// ---- constants ----
// B=2, S=2048, D=768, HD=64, NH=12, NKV=4, GROUPS=3, WINDOW=384, theta=1e4, eps=1e-6
// I/O dtype: float32. Workspace intermediates: bf16.

__device__ __forceinline__ void load4bf(const bf16* p, float f[4]) {
    uint2 u = *reinterpret_cast<const uint2*>(p);
    f[0] = __uint_as_float((u.x & 0xffffu) << 16);
    f[1] = __uint_as_float(u.x & 0xffff0000u);
    f[2] = __uint_as_float((u.y & 0xffffu) << 16);
    f[3] = __uint_as_float(u.y & 0xffff0000u);
}

// ================= Kernel 1: QKV GEMM + per-head RMSNorm + RoPE =================
// grid (64 m-tiles, 20 n-tiles). n-tiles 0-11: q heads; 12-15: k heads; 16-19: v heads.
__global__ __launch_bounds__(256) void k_qkv(
    const float* __restrict__ hs, const float* __restrict__ qw,
    const float* __restrict__ kw, const float* __restrict__ vw,
    const float* __restrict__ qln, const float* __restrict__ kln,
    bf16* __restrict__ qo, bf16* __restrict__ ko, bf16* __restrict__ vo)
{
    __shared__ float As[64][20];   // stride 20 floats: 16B-aligned rows, spread banks
    __shared__ float Bs[64][20];
    const int tid = threadIdx.x;
    const int tx = tid & 15, ty = tid >> 4;
    const int m0 = blockIdx.x * 64;
    const int nblk = blockIdx.y;

    const float* wsrc; int wrow0, kind, head;
    if (nblk < 12)      { wsrc = qw; wrow0 = nblk * 64;        kind = 0; head = nblk; }
    else if (nblk < 16) { wsrc = kw; wrow0 = (nblk - 12) * 64; kind = 1; head = nblk - 12; }
    else                { wsrc = vw; wrow0 = (nblk - 16) * 64; kind = 2; head = nblk - 16; }

    const int lr = tid >> 2;          // 0..63 row within tile
    const int lk = (tid & 3) * 4;     // 0,4,8,12 within k-chunk
    const float* aptr = hs   + (size_t)(m0 + lr) * 768 + lk;
    const float* bptr = wsrc + (size_t)(wrow0 + lr) * 768 + lk;

    float c[4][4] = {};

    for (int k0 = 0; k0 < 768; k0 += 16) {
        float4 fa = *reinterpret_cast<const float4*>(aptr + k0);
        float4 fb = *reinterpret_cast<const float4*>(bptr + k0);
        __syncthreads();
        As[lr][lk]   = fa.x; As[lr][lk+1] = fa.y; As[lr][lk+2] = fa.z; As[lr][lk+3] = fa.w;
        Bs[lr][lk]   = fb.x; Bs[lr][lk+1] = fb.y; Bs[lr][lk+2] = fb.z; Bs[lr][lk+3] = fb.w;
        __syncthreads();
        #pragma unroll
        for (int kk = 0; kk < 16; kk += 4) {
            float4 a4[4], b4[4];
            #pragma unroll
            for (int i = 0; i < 4; ++i) a4[i] = *reinterpret_cast<const float4*>(&As[ty + 16 * i][kk]);
            #pragma unroll
            for (int j = 0; j < 4; ++j) b4[j] = *reinterpret_cast<const float4*>(&Bs[tx + 16 * j][kk]);
            #pragma unroll
            for (int i = 0; i < 4; ++i)
                #pragma unroll
                for (int j = 0; j < 4; ++j) {
                    c[i][j] += a4[i].x * b4[j].x;
                    c[i][j] += a4[i].y * b4[j].y;
                    c[i][j] += a4[i].z * b4[j].z;
                    c[i][j] += a4[i].w * b4[j].w;
                }
        }
    }

    const int b  = m0 >> 11;     // batch
    const int s0 = m0 & 2047;    // seq offset of tile

    if (kind == 2) {  // V: passthrough
        bf16* base = vo + ((size_t)(b * 4 + head) * 2048 + s0) * 64;
        #pragma unroll
        for (int i = 0; i < 4; ++i) {
            bf16* dst = base + (size_t)(ty + 16 * i) * 64;
            #pragma unroll
            for (int j = 0; j < 4; ++j) dst[tx + 16 * j] = __float2bfloat16(c[i][j]);
        }
        return;
    }

    const float* ln = (kind == 0) ? qln : kln;
    float lw[4];
    #pragma unroll
    for (int j = 0; j < 4; ++j) lw[j] = ln[tx + 16 * j];

    // inv_freq[f] = 10000^(-f/32); thread owns freqs tx (cols tx & tx+32) and tx+16 (cols tx+16 & tx+48)
    const float KLN = 0.28782313662425572f;  // ln(10000)/32
    const float if0 = expf(-(float)tx * KLN);
    const float if1 = expf(-(float)(tx + 16) * KLN);
    bf16* base = (kind == 0) ? qo + ((size_t)(b * 12 + head) * 2048 + s0) * 64
                             : ko + ((size_t)(b * 4  + head) * 2048 + s0) * 64;
    #pragma unroll
    for (int i = 0; i < 4; ++i) {
        float ss = c[i][0]*c[i][0] + c[i][1]*c[i][1] + c[i][2]*c[i][2] + c[i][3]*c[i][3];
        ss += __shfl_xor(ss, 1);
        ss += __shfl_xor(ss, 2);
        ss += __shfl_xor(ss, 4);
        ss += __shfl_xor(ss, 8);
        float rms = rsqrtf(ss * (1.0f / 64.0f) + 1e-6f);
        float n0 = c[i][0] * rms * lw[0];
        float n1 = c[i][1] * rms * lw[1];
        float n2 = c[i][2] * rms * lw[2];
        float n3 = c[i][3] * rms * lw[3];
        const int s = s0 + ty + 16 * i;
        float sn0, cs0, sn1, cs1;
        sincosf((float)s * if0, &sn0, &cs0);
        sincosf((float)s * if1, &sn1, &cs1);
        bf16* dst = base + (size_t)(ty + 16 * i) * 64;
        dst[tx]      = __float2bfloat16(n0 * cs0 - n2 * sn0);  // first half: x*cos - x[d+32]*sin
        dst[tx + 16] = __float2bfloat16(n1 * cs1 - n3 * sn1);
        dst[tx + 32] = __float2bfloat16(n2 * cs0 + n0 * sn0);  // second half: x*cos + x[d-32]*sin
        dst[tx + 48] = __float2bfloat16(n3 * cs1 + n1 * sn1);
    }
}

// ================= Kernel 2: sliding-window causal attention =================
// grid (32 q-tiles, 12 heads, 2 batch); window 384 -> key tiles kb in [qb-6, qb]
__global__ __launch_bounds__(256) void k_attn(
    const bf16* __restrict__ qi, const bf16* __restrict__ ki, const bf16* __restrict__ vi,
    bf16* __restrict__ ao)
{
    __shared__ float Qs[64][68];
    __shared__ float Ks[64][68];
    __shared__ float Vt[64][68];   // transposed: Vt[d][key]
    __shared__ bf16  Ps[64][68];   // P tile, bf16
    const int tid = threadIdx.x, tx = tid & 15, ty = tid >> 4;
    const int qb = blockIdx.x, h = blockIdx.y, b = blockIdx.z;
    const int kv = h / 3;          // GQA group of 3
    const int q0 = qb * 64;

    const bf16* qsrc = qi + ((size_t)(b * 12 + h) * 2048 + q0) * 64;
    for (int idx = tid; idx < 1024; idx += 256) {
        int r = idx >> 4, d = (idx & 15) * 4;
        float f[4]; load4bf(qsrc + r * 64 + d, f);
        Qs[r][d] = f[0]; Qs[r][d+1] = f[1]; Qs[r][d+2] = f[2]; Qs[r][d+3] = f[3];
    }

    float m_[4], l_[4], o_[4][4];
    #pragma unroll
    for (int i = 0; i < 4; ++i) {
        m_[i] = -INFINITY; l_[i] = 0.f;
        #pragma unroll
        for (int j = 0; j < 4; ++j) o_[i][j] = 0.f;
    }

    const int kb_lo = (qb > 6) ? (qb - 6) : 0;
    for (int kb = kb_lo; kb <= qb; ++kb) {
        const int k0 = kb * 64;
        __syncthreads();   // protect prior-iter reads of Ks/Vt/Ps (and Q staging on iter 1)
        const bf16* ksrc = ki + ((size_t)(b * 4 + kv) * 2048 + k0) * 64;
        const bf16* vsrc = vi + ((size_t)(b * 4 + kv) * 2048 + k0) * 64;
        for (int idx = tid; idx < 1024; idx += 256) {
            int r = idx >> 4, d = (idx & 15) * 4;
            float f[4]; load4bf(ksrc + r * 64 + d, f);
            Ks[r][d] = f[0]; Ks[r][d+1] = f[1]; Ks[r][d+2] = f[2]; Ks[r][d+3] = f[3];
            float g[4]; load4bf(vsrc + r * 64 + d, g);
            Vt[d][r] = g[0]; Vt[d+1][r] = g[1]; Vt[d+2][r] = g[2]; Vt[d+3][r] = g[3];
        }
        __syncthreads();

        // S = Q K^T
        float sc[4][4] = {};
        #pragma unroll
        for (int d = 0; d < 64; d += 4) {
            float4 a4[4], b4[4];
            #pragma unroll
            for (int i = 0; i < 4; ++i) a4[i] = *reinterpret_cast<const float4*>(&Qs[ty + 16 * i][d]);
            #pragma unroll
            for (int j = 0; j < 4; ++j) b4[j] = *reinterpret_cast<const float4*>(&Ks[tx + 16 * j][d]);
            #pragma unroll
            for (int i = 0; i < 4; ++i)
                #pragma unroll
                for (int j = 0; j < 4; ++j) {
                    sc[i][j] += a4[i].x * b4[j].x;
                    sc[i][j] += a4[i].y * b4[j].y;
                    sc[i][j] += a4[i].z * b4[j].z;
                    sc[i][j] += a4[i].w * b4[j].w;
                }
        }

        // mask + online softmax (row stats across the 16-lane tx group)
        #pragma unroll
        for (int i = 0; i < 4; ++i) {
            const int qg = q0 + ty + 16 * i;
            float tmax = -INFINITY;
            float p[4];
            #pragma unroll
            for (int j = 0; j < 4; ++j) {
                int kg = k0 + tx + 16 * j;
                bool ok = (kg <= qg) && (kg > qg - 384);
                sc[i][j] = ok ? sc[i][j] * 0.125f : -INFINITY;
                tmax = fmaxf(tmax, sc[i][j]);
            }
            tmax = fmaxf(tmax, __shfl_xor(tmax, 1));
            tmax = fmaxf(tmax, __shfl_xor(tmax, 2));
            tmax = fmaxf(tmax, __shfl_xor(tmax, 4));
            tmax = fmaxf(tmax, __shfl_xor(tmax, 8));
            float mnew = fmaxf(m_[i], tmax);
            float scale;
            if (mnew > -INFINITY) {
                scale = expf(m_[i] - mnew);   // m_=-inf -> 0
                #pragma unroll
                for (int j = 0; j < 4; ++j) p[j] = expf(sc[i][j] - mnew);  // -inf -> 0
            } else {
                scale = 1.0f;
                #pragma unroll
                for (int j = 0; j < 4; ++j) p[j] = 0.0f;
            }
            m_[i] = mnew;
            float rs = p[0] + p[1] + p[2] + p[3];
            rs += __shfl_xor(rs, 1);
            rs += __shfl_xor(rs, 2);
            rs += __shfl_xor(rs, 4);
            rs += __shfl_xor(rs, 8);
            l_[i] = l_[i] * scale + rs;
            #pragma unroll
            for (int j = 0; j < 4; ++j) o_[i][j] *= scale;
            #pragma unroll
            for (int j = 0; j < 4; ++j) Ps[ty + 16 * i][tx + 16 * j] = __float2bfloat16(p[j]);
        }
        __syncthreads();

        // O += P V
        #pragma unroll
        for (int k = 0; k < 64; k += 4) {
            float pa[4][4]; float4 vb[4];
            #pragma unroll
            for (int i = 0; i < 4; ++i) load4bf(&Ps[ty + 16 * i][k], pa[i]);
            #pragma unroll
            for (int j = 0; j < 4; ++j) vb[j] = *reinterpret_cast<const float4*>(&Vt[tx + 16 * j][k]);
            #pragma unroll
            for (int i = 0; i < 4; ++i)
                #pragma unroll
                for (int j = 0; j < 4; ++j) {
                    o_[i][j] += pa[i][0] * vb[j].x;
                    o_[i][j] += pa[i][1] * vb[j].y;
                    o_[i][j] += pa[i][2] * vb[j].z;
                    o_[i][j] += pa[i][3] * vb[j].w;
                }
        }
    }

    #pragma unroll
    for (int i = 0; i < 4; ++i) {
        float inv = 1.0f / l_[i];   // diag key always allowed -> l_ > 0
        bf16* dst = ao + ((size_t)(b * 2048 + q0 + ty + 16 * i)) * 768 + h * 64;
        #pragma unroll
        for (int j = 0; j < 4; ++j) dst[tx + 16 * j] = __float2bfloat16(o_[i][j] * inv);
    }
}

// ================= Kernel 3: output projection (A: bf16 ws, W: fp32, out: fp32) ===
__global__ __launch_bounds__(256) void k_oproj(
    const bf16* __restrict__ A, const float* __restrict__ W, float* __restrict__ out)
{
    __shared__ float As[64][20];
    __shared__ float Bs[64][20];
    const int tid = threadIdx.x, tx = tid & 15, ty = tid >> 4;
    const int m0 = blockIdx.x * 64, n0 = blockIdx.y * 64;
    const int lr = tid >> 2, lk = (tid & 3) * 4;
    const bf16*  aptr = A + (size_t)(m0 + lr) * 768 + lk;
    const float* bptr = W + (size_t)(n0 + lr) * 768 + lk;
    float c[4][4] = {};
    for (int k0 = 0; k0 < 768; k0 += 16) {
        float fa[4]; load4bf(aptr + k0, fa);
        float4 fb = *reinterpret_cast<const float4*>(bptr + k0);
        __syncthreads();
        As[lr][lk]   = fa[0]; As[lr][lk+1] = fa[1]; As[lr][lk+2] = fa[2]; As[lr][lk+3] = fa[3];
        Bs[lr][lk]   = fb.x;  Bs[lr][lk+1] = fb.y;  Bs[lr][lk+2] = fb.z;  Bs[lr][lk+3] = fb.w;
        __syncthreads();
        #pragma unroll
        for (int kk = 0; kk < 16; kk += 4) {
            float4 a4[4], b4[4];
            #pragma unroll
            for (int i = 0; i < 4; ++i) a4[i] = *reinterpret_cast<const float4*>(&As[ty + 16 * i][kk]);
            #pragma unroll
            for (int j = 0; j < 4; ++j) b4[j] = *reinterpret_cast<const float4*>(&Bs[tx + 16 * j][kk]);
            #pragma unroll
            for (int i = 0; i < 4; ++i)
                #pragma unroll
                for (int j = 0; j < 4; ++j) {
                    c[i][j] += a4[i].x * b4[j].x;
                    c[i][j] += a4[i].y * b4[j].y;
                    c[i][j] += a4[i].z * b4[j].z;
                    c[i][j] += a4[i].w * b4[j].w;
                }
        }
    }
    #pragma unroll
    for (int i = 0; i < 4; ++i) {
        float* dst = out + (size_t)(m0 + ty + 16 * i) * 768 + n0;
        #pragma unroll
        for (int j = 0; j < 4; ++j) dst[tx + 16 * j] = c[i][j];
    }
}

extern "C" void kernel_launch(void* const* d_in, const int* in_sizes, int n_in,
                              void* d_out, int out_size, void* d_ws, size_t ws_size,
                              hipStream_t stream) {
    const float* hs  = (const float*)d_in[0];
    const float* qw  = (const float*)d_in[1];
    const float* kw  = (const float*)d_in[2];
    const float* vw  = (const float*)d_in[3];
    const float* ow  = (const float*)d_in[4];
    const float* qln = (const float*)d_in[5];
    const float* kln = (const float*)d_in[6];
    float* out = (float*)d_out;

    // workspace (bf16): q[2*12*2048*64] k[2*4*2048*64] v[same] attn[2*2048*768] = 16.8 MB
    bf16* q_ws = (bf16*)d_ws;
    bf16* k_ws = q_ws + 3145728;
    bf16* v_ws = k_ws + 1048576;
    bf16* a_ws = v_ws + 1048576;

    k_qkv<<<dim3(64, 20, 1), 256, 0, stream>>>(hs, qw, kw, vw, qln, kln, q_ws, k_ws, v_ws);
    k_attn<<<dim3(32, 12, 2), 256, 0, stream>>>(q_ws, k_ws, v_ws, a_ws);
    k_oproj<<<dim3(64, 12, 1), 256, 0, stream>>>(a_ws, ow, out);
}

// Round 3
// 251.895 us; speedup vs baseline: 1.9508x; 1.9508x over previous
//
#include <hip/hip_runtime.h>
#include <hip/hip_bf16.h>

typedef __hip_bfloat16 bf16;
typedef __attribute__((ext_vector_type(8))) short bf16x8;   // 8 bf16 = 4 VGPR
typedef __attribute__((ext_vector_type(4))) float f32x4;

#define MFMA16(a, b, c) __builtin_amdgcn_mfma_f32_16x16x32_bf16((a), (b), (c), 0, 0, 0)

// ---- constants ----
// B=2, S=2048, D=768, HD=64, NH=12, NKV=4, GROUPS=3, WINDOW=384, theta=1e4, eps=1e-6
// I/O dtype: float32. Workspace intermediates: bf16. V is stored TRANSPOSED [b][kv][d][s].

// ================= Kernel 1: QKV GEMM + per-head RMSNorm + RoPE =================
// grid (64 m-tiles, 20 n-tiles). n-tiles 0-11: q heads; 12-15: k heads; 16-19: v heads.
__global__ __launch_bounds__(256) void k_qkv(
    const float* __restrict__ hs, const float* __restrict__ qw,
    const float* __restrict__ kw, const float* __restrict__ vw,
    const float* __restrict__ qln, const float* __restrict__ kln,
    bf16* __restrict__ qo, bf16* __restrict__ ko, bf16* __restrict__ vto)
{
    __shared__ float As[64][20];
    __shared__ float Bs[64][20];
    const int tid = threadIdx.x;
    const int tx = tid & 15, ty = tid >> 4;
    const int m0 = blockIdx.x * 64;
    const int nblk = blockIdx.y;

    const float* wsrc; int wrow0, kind, head;
    if (nblk < 12)      { wsrc = qw; wrow0 = nblk * 64;        kind = 0; head = nblk; }
    else if (nblk < 16) { wsrc = kw; wrow0 = (nblk - 12) * 64; kind = 1; head = nblk - 12; }
    else                { wsrc = vw; wrow0 = (nblk - 16) * 64; kind = 2; head = nblk - 16; }

    const int lr = tid >> 2;
    const int lk = (tid & 3) * 4;
    const float* aptr = hs   + (size_t)(m0 + lr) * 768 + lk;
    const float* bptr = wsrc + (size_t)(wrow0 + lr) * 768 + lk;

    float c[4][4] = {};

    for (int k0 = 0; k0 < 768; k0 += 16) {
        float4 fa = *reinterpret_cast<const float4*>(aptr + k0);
        float4 fb = *reinterpret_cast<const float4*>(bptr + k0);
        __syncthreads();
        As[lr][lk]   = fa.x; As[lr][lk+1] = fa.y; As[lr][lk+2] = fa.z; As[lr][lk+3] = fa.w;
        Bs[lr][lk]   = fb.x; Bs[lr][lk+1] = fb.y; Bs[lr][lk+2] = fb.z; Bs[lr][lk+3] = fb.w;
        __syncthreads();
        #pragma unroll
        for (int kk = 0; kk < 16; kk += 4) {
            float4 a4[4], b4[4];
            #pragma unroll
            for (int i = 0; i < 4; ++i) a4[i] = *reinterpret_cast<const float4*>(&As[ty + 16 * i][kk]);
            #pragma unroll
            for (int j = 0; j < 4; ++j) b4[j] = *reinterpret_cast<const float4*>(&Bs[tx + 16 * j][kk]);
            #pragma unroll
            for (int i = 0; i < 4; ++i)
                #pragma unroll
                for (int j = 0; j < 4; ++j) {
                    c[i][j] += a4[i].x * b4[j].x;
                    c[i][j] += a4[i].y * b4[j].y;
                    c[i][j] += a4[i].z * b4[j].z;
                    c[i][j] += a4[i].w * b4[j].w;
                }
        }
    }

    const int b  = m0 >> 11;
    const int s0 = m0 & 2047;

    if (kind == 2) {  // V: write TRANSPOSED [b][kv][d][s]
        bf16* base = vto + (size_t)(b * 4 + head) * 64 * 2048;
        #pragma unroll
        for (int i = 0; i < 4; ++i)
            #pragma unroll
            for (int j = 0; j < 4; ++j)
                base[(size_t)(tx + 16 * j) * 2048 + (s0 + ty + 16 * i)] = __float2bfloat16(c[i][j]);
        return;
    }

    const float* ln = (kind == 0) ? qln : kln;
    float lw[4];
    #pragma unroll
    for (int j = 0; j < 4; ++j) lw[j] = ln[tx + 16 * j];

    const float KLN = 0.28782313662425572f;  // ln(10000)/32
    const float if0 = expf(-(float)tx * KLN);
    const float if1 = expf(-(float)(tx + 16) * KLN);
    bf16* base = (kind == 0) ? qo + ((size_t)(b * 12 + head) * 2048 + s0) * 64
                             : ko + ((size_t)(b * 4  + head) * 2048 + s0) * 64;
    #pragma unroll
    for (int i = 0; i < 4; ++i) {
        float ss = c[i][0]*c[i][0] + c[i][1]*c[i][1] + c[i][2]*c[i][2] + c[i][3]*c[i][3];
        ss += __shfl_xor(ss, 1);
        ss += __shfl_xor(ss, 2);
        ss += __shfl_xor(ss, 4);
        ss += __shfl_xor(ss, 8);
        float rms = rsqrtf(ss * (1.0f / 64.0f) + 1e-6f);
        float n0 = c[i][0] * rms * lw[0];
        float n1 = c[i][1] * rms * lw[1];
        float n2 = c[i][2] * rms * lw[2];
        float n3 = c[i][3] * rms * lw[3];
        const int s = s0 + ty + 16 * i;
        float sn0, cs0, sn1, cs1;
        sincosf((float)s * if0, &sn0, &cs0);
        sincosf((float)s * if1, &sn1, &cs1);
        bf16* dst = base + (size_t)(ty + 16 * i) * 64;
        dst[tx]      = __float2bfloat16(n0 * cs0 - n2 * sn0);
        dst[tx + 16] = __float2bfloat16(n1 * cs1 - n3 * sn1);
        dst[tx + 32] = __float2bfloat16(n2 * cs0 + n0 * sn0);
        dst[tx + 48] = __float2bfloat16(n3 * cs1 + n1 * sn1);
    }
}

// ================= Kernel 2: MFMA sliding-window attention =================
// grid (32 q-tiles, 12 heads, 2 batch); 4 waves/block, wave w owns q-rows [16w,16w+16)
__global__ __launch_bounds__(256) void k_attn(
    const bf16* __restrict__ qi, const bf16* __restrict__ ki,
    const bf16* __restrict__ vti, bf16* __restrict__ ao)
{
    __shared__ bf16 Ks[64 * 72];   // [key][d], stride 72
    __shared__ bf16 Vs[64 * 72];   // [d][key], stride 72
    __shared__ bf16 Ps[64 * 72];   // [q][key], stride 72, per-wave-private rows
    const int tid = threadIdx.x;
    const int w = tid >> 6, l = tid & 63;
    const int lm = l & 15, lg = l >> 4;
    const int qb = blockIdx.x, h = blockIdx.y, b = blockIdx.z;
    const int kv = h / 3;
    const int q0 = qb * 64;

    // Q fragments (A operand): lane holds Q[q=lm (of wave tile)][k = lg*8 + j], 2 k-chunks
    const bf16* qbase = qi + ((size_t)((b * 12 + h) * 2048 + q0 + w * 16 + lm)) * 64 + lg * 8;
    bf16x8 qf0 = *(const bf16x8*)(qbase);
    bf16x8 qf1 = *(const bf16x8*)(qbase + 32);

    f32x4 oacc[4] = {};
    float m_[4], l_[4];
    #pragma unroll
    for (int r = 0; r < 4; ++r) { m_[r] = -INFINITY; l_[r] = 0.f; }

    const int sr = tid >> 2, sc = (tid & 3) * 16;   // staging: row, col-chunk
    const bf16* kgb = ki  + (size_t)(b * 4 + kv) * 2048 * 64;
    const bf16* vgb = vti + (size_t)(b * 4 + kv) * 64 * 2048;

    const int kb_lo = (qb > 6) ? (qb - 6) : 0;
    for (int kb = kb_lo; kb <= qb; ++kb) {
        const int k0 = kb * 64;
        __syncthreads();   // prior iteration's Ks/Vs reads done
        {
            const bf16* kp = kgb + (size_t)(k0 + sr) * 64 + sc;
            bf16x8 t0 = *(const bf16x8*)(kp);
            bf16x8 t1 = *(const bf16x8*)(kp + 8);
            const bf16* vp = vgb + (size_t)sr * 2048 + k0 + sc;
            bf16x8 t2 = *(const bf16x8*)(vp);
            bf16x8 t3 = *(const bf16x8*)(vp + 8);
            *(bf16x8*)(&Ks[sr * 72 + sc])     = t0;
            *(bf16x8*)(&Ks[sr * 72 + sc + 8]) = t1;
            *(bf16x8*)(&Vs[sr * 72 + sc])     = t2;
            *(bf16x8*)(&Vs[sr * 72 + sc + 8]) = t3;
        }
        __syncthreads();

        // S = Q K^T : D[row=q-local (lg*4+r)][col=key (lm)], 4 key-tiles
        f32x4 sacc[4];
        #pragma unroll
        for (int kt = 0; kt < 4; ++kt) {
            bf16x8 kf0 = *(const bf16x8*)(&Ks[(kt * 16 + lm) * 72 + lg * 8]);
            bf16x8 kf1 = *(const bf16x8*)(&Ks[(kt * 16 + lm) * 72 + 32 + lg * 8]);
            f32x4 z = {0.f, 0.f, 0.f, 0.f};
            z = MFMA16(qf0, kf0, z);
            sacc[kt] = MFMA16(qf1, kf1, z);
        }

        // mask + row max
        float pmax[4] = {-INFINITY, -INFINITY, -INFINITY, -INFINITY};
        #pragma unroll
        for (int kt = 0; kt < 4; ++kt)
            #pragma unroll
            for (int r = 0; r < 4; ++r) {
                int kgl = k0 + kt * 16 + lm;
                int qgl = q0 + w * 16 + lg * 4 + r;
                bool ok = (kgl <= qgl) && (kgl > qgl - 384);
                float s = ok ? sacc[kt][r] * 0.125f : -INFINITY;
                sacc[kt][r] = s;
                pmax[r] = fmaxf(pmax[r], s);
            }
        #pragma unroll
        for (int r = 0; r < 4; ++r) {
            float t = pmax[r];
            t = fmaxf(t, __shfl_xor(t, 1));
            t = fmaxf(t, __shfl_xor(t, 2));
            t = fmaxf(t, __shfl_xor(t, 4));
            t = fmaxf(t, __shfl_xor(t, 8));
            pmax[r] = t;
        }

        // online softmax; write P to per-wave LDS rows (no barrier needed)
        #pragma unroll
        for (int r = 0; r < 4; ++r) {
            float mnew = fmaxf(m_[r], pmax[r]);
            float scale, rs = 0.f, p[4];
            if (mnew > -INFINITY) {
                scale = expf(m_[r] - mnew);   // expf(-inf)=0 handles first valid tile
                #pragma unroll
                for (int kt = 0; kt < 4; ++kt) { p[kt] = expf(sacc[kt][r] - mnew); rs += p[kt]; }
            } else {            // fully-masked tile for this row (window leading edge)
                scale = 1.f;
                #pragma unroll
                for (int kt = 0; kt < 4; ++kt) p[kt] = 0.f;
            }
            m_[r] = mnew;
            rs += __shfl_xor(rs, 1);
            rs += __shfl_xor(rs, 2);
            rs += __shfl_xor(rs, 4);
            rs += __shfl_xor(rs, 8);
            l_[r] = l_[r] * scale + rs;
            #pragma unroll
            for (int dt = 0; dt < 4; ++dt) oacc[dt][r] *= scale;
            #pragma unroll
            for (int kt = 0; kt < 4; ++kt)
                Ps[(w * 16 + lg * 4 + r) * 72 + kt * 16 + lm] = __float2bfloat16(p[kt]);
        }

        // O += P V : A = P[q=lm][k=lg*8+j], B = V[k][d] read from Vs[d][key]
        bf16x8 pf0 = *(const bf16x8*)(&Ps[(w * 16 + lm) * 72 + lg * 8]);
        bf16x8 pf1 = *(const bf16x8*)(&Ps[(w * 16 + lm) * 72 + 32 + lg * 8]);
        #pragma unroll
        for (int dt = 0; dt < 4; ++dt) {
            bf16x8 vf0 = *(const bf16x8*)(&Vs[(dt * 16 + lm) * 72 + lg * 8]);
            bf16x8 vf1 = *(const bf16x8*)(&Vs[(dt * 16 + lm) * 72 + 32 + lg * 8]);
            oacc[dt] = MFMA16(pf0, vf0, oacc[dt]);
            oacc[dt] = MFMA16(pf1, vf1, oacc[dt]);
        }
    }

    #pragma unroll
    for (int r = 0; r < 4; ++r) {
        float inv = 1.f / l_[r];   // diagonal key always allowed -> l_ > 0
        bf16* dst = ao + ((size_t)(b * 2048 + q0 + w * 16 + lg * 4 + r)) * 768 + h * 64;
        #pragma unroll
        for (int dt = 0; dt < 4; ++dt)
            dst[dt * 16 + lm] = __float2bfloat16(oacc[dt][r] * inv);
    }
}

// ================= Kernel 3: output projection (A: bf16 ws, W: fp32, out: fp32) ===
__global__ __launch_bounds__(256) void k_oproj(
    const bf16* __restrict__ A, const float* __restrict__ W, float* __restrict__ out)
{
    __shared__ float As[64][20];
    __shared__ float Bs[64][20];
    const int tid = threadIdx.x, tx = tid & 15, ty = tid >> 4;
    const int m0 = blockIdx.x * 64, n0 = blockIdx.y * 64;
    const int lr = tid >> 2, lk = (tid & 3) * 4;
    const bf16*  aptr = A + (size_t)(m0 + lr) * 768 + lk;
    const float* bptr = W + (size_t)(n0 + lr) * 768 + lk;
    float c[4][4] = {};
    for (int k0 = 0; k0 < 768; k0 += 16) {
        uint2 u = *reinterpret_cast<const uint2*>(aptr + k0);
        float fa0 = __uint_as_float((u.x & 0xffffu) << 16);
        float fa1 = __uint_as_float(u.x & 0xffff0000u);
        float fa2 = __uint_as_float((u.y & 0xffffu) << 16);
        float fa3 = __uint_as_float(u.y & 0xffff0000u);
        float4 fb = *reinterpret_cast<const float4*>(bptr + k0);
        __syncthreads();
        As[lr][lk]   = fa0; As[lr][lk+1] = fa1; As[lr][lk+2] = fa2; As[lr][lk+3] = fa3;
        Bs[lr][lk]   = fb.x; Bs[lr][lk+1] = fb.y; Bs[lr][lk+2] = fb.z; Bs[lr][lk+3] = fb.w;
        __syncthreads();
        #pragma unroll
        for (int kk = 0; kk < 16; kk += 4) {
            float4 a4[4], b4[4];
            #pragma unroll
            for (int i = 0; i < 4; ++i) a4[i] = *reinterpret_cast<const float4*>(&As[ty + 16 * i][kk]);
            #pragma unroll
            for (int j = 0; j < 4; ++j) b4[j] = *reinterpret_cast<const float4*>(&Bs[tx + 16 * j][kk]);
            #pragma unroll
            for (int i = 0; i < 4; ++i)
                #pragma unroll
                for (int j = 0; j < 4; ++j) {
                    c[i][j] += a4[i].x * b4[j].x;
                    c[i][j] += a4[i].y * b4[j].y;
                    c[i][j] += a4[i].z * b4[j].z;
                    c[i][j] += a4[i].w * b4[j].w;
                }
        }
    }
    #pragma unroll
    for (int i = 0; i < 4; ++i) {
        float* dst = out + (size_t)(m0 + ty + 16 * i) * 768 + n0;
        #pragma unroll
        for (int j = 0; j < 4; ++j) dst[tx + 16 * j] = c[i][j];
    }
}

extern "C" void kernel_launch(void* const* d_in, const int* in_sizes, int n_in,
                              void* d_out, int out_size, void* d_ws, size_t ws_size,
                              hipStream_t stream) {
    const float* hs  = (const float*)d_in[0];
    const float* qw  = (const float*)d_in[1];
    const float* kw  = (const float*)d_in[2];
    const float* vw  = (const float*)d_in[3];
    const float* ow  = (const float*)d_in[4];
    const float* qln = (const float*)d_in[5];
    const float* kln = (const float*)d_in[6];
    float* out = (float*)d_out;

    // workspace (bf16): q[2*12*2048*64] k[2*4*2048*64] vT[2*4*64*2048] attn[2*2048*768] = 16.8 MB
    bf16* q_ws  = (bf16*)d_ws;
    bf16* k_ws  = q_ws + 3145728;
    bf16* vt_ws = k_ws + 1048576;
    bf16* a_ws  = vt_ws + 1048576;

    k_qkv<<<dim3(64, 20, 1), 256, 0, stream>>>(hs, qw, kw, vw, qln, kln, q_ws, k_ws, vt_ws);
    k_attn<<<dim3(32, 12, 2), 256, 0, stream>>>(q_ws, k_ws, vt_ws, a_ws);
    k_oproj<<<dim3(64, 12, 1), 256, 0, stream>>>(a_ws, ow, out);
}

// Round 4
// 82.970 us; speedup vs baseline: 5.9227x; 3.0360x over previous
//
#include <hip/hip_runtime.h>
#include <hip/hip_bf16.h>

typedef __hip_bfloat16 bf16;
typedef __attribute__((ext_vector_type(8))) short bf16x8;   // 8 bf16 = 4 VGPR
typedef __attribute__((ext_vector_type(4))) float f32x4;

#define MFMA16(a, b, c) __builtin_amdgcn_mfma_f32_16x16x32_bf16((a), (b), (c), 0, 0, 0)

// ---- constants ----
// B=2, S=2048, D=768, HD=64, NH=12, NKV=4, GROUPS=3, WINDOW=384, theta=1e4, eps=1e-6
// I/O fp32; workspace intermediates bf16; V stored transposed [b][kv][d][s].

__device__ __forceinline__ void st4bf(bf16* p, float4 v) {
    bf16 t[4];
    t[0] = __float2bfloat16(v.x); t[1] = __float2bfloat16(v.y);
    t[2] = __float2bfloat16(v.z); t[3] = __float2bfloat16(v.w);
    *reinterpret_cast<uint2*>(p) = *reinterpret_cast<const uint2*>(t);
}

// ============ Kernel 0: RoPE cos/sin table [s][f] f=0..31, float2(cos,sin) ============
__global__ __launch_bounds__(256) void k_tab(float2* __restrict__ tab) {
    int i = blockIdx.x * 256 + threadIdx.x;     // 2048*32 entries
    int s = i >> 5, f = i & 31;
    float ang = (float)s * expf(-(float)f * 0.28782313662425572f);  // ln(1e4)/32
    float sn, cs;
    sincosf(ang, &sn, &cs);
    tab[i] = make_float2(cs, sn);
}

// ================= Kernel 1: MFMA QKV GEMM + RMSNorm + RoPE =================
// grid (64 m-tiles, 20 n-blocks): 0-11 q heads, 12-15 k heads, 16-19 v heads.
// 4 waves; wave w owns rows [16w,16w+16) of the 64x64 tile.
__global__ __launch_bounds__(256) void k_qkv(
    const float* __restrict__ hs, const float* __restrict__ qw,
    const float* __restrict__ kw, const float* __restrict__ vw,
    const float* __restrict__ qln, const float* __restrict__ kln,
    const float2* __restrict__ tab,
    bf16* __restrict__ qo, bf16* __restrict__ ko, bf16* __restrict__ vto)
{
    __shared__ bf16 As[64 * 72];
    __shared__ bf16 Bs[64 * 72];
    const int tid = threadIdx.x;
    const int w = tid >> 6, l = tid & 63;
    const int lm = l & 15, lg = l >> 4;
    const int m0 = blockIdx.x * 64;
    const int nblk = blockIdx.y;

    const float* wsrc; int wrow0, kind, head;
    if (nblk < 12)      { wsrc = qw; wrow0 = nblk * 64;        kind = 0; head = nblk; }
    else if (nblk < 16) { wsrc = kw; wrow0 = (nblk - 12) * 64; kind = 1; head = nblk - 12; }
    else                { wsrc = vw; wrow0 = (nblk - 16) * 64; kind = 2; head = nblk - 16; }

    // staging: thread -> row sr, 4 float4 chunks at cols lk+{0,16,32,48}
    const int sr = tid >> 2, lk = (tid & 3) * 4;
    const float* aptr = hs   + (size_t)(m0 + sr) * 768 + lk;
    const float* bptr = wsrc + (size_t)(wrow0 + sr) * 768 + lk;

    f32x4 acc[4] = {};

    for (int k0 = 0; k0 < 768; k0 += 64) {
        float4 fa[4], fb[4];
        #pragma unroll
        for (int i = 0; i < 4; ++i) {
            fa[i] = *reinterpret_cast<const float4*>(aptr + k0 + 16 * i);
            fb[i] = *reinterpret_cast<const float4*>(bptr + k0 + 16 * i);
        }
        __syncthreads();   // prior compute reads done
        #pragma unroll
        for (int i = 0; i < 4; ++i) {
            st4bf(&As[sr * 72 + lk + 16 * i], fa[i]);
            st4bf(&Bs[sr * 72 + lk + 16 * i], fb[i]);
        }
        __syncthreads();
        #pragma unroll
        for (int kk = 0; kk < 2; ++kk) {
            bf16x8 af = *(const bf16x8*)(&As[(w * 16 + lm) * 72 + kk * 32 + lg * 8]);
            #pragma unroll
            for (int ct = 0; ct < 4; ++ct) {
                bf16x8 bfr = *(const bf16x8*)(&Bs[(ct * 16 + lm) * 72 + kk * 32 + lg * 8]);
                acc[ct] = MFMA16(af, bfr, acc[ct]);
            }
        }
    }

    const int b  = m0 >> 11;
    const int s0 = m0 & 2047;

    if (kind == 2) {  // V: write TRANSPOSED [b][kv][d][s]
        bf16* base = vto + (size_t)(b * 4 + head) * 64 * 2048;
        #pragma unroll
        for (int r = 0; r < 4; ++r) {
            const int s = s0 + w * 16 + lg * 4 + r;
            #pragma unroll
            for (int ct = 0; ct < 4; ++ct)
                base[(size_t)(ct * 16 + lm) * 2048 + s] = __float2bfloat16(acc[ct][r]);
        }
        return;
    }

    const float* ln = (kind == 0) ? qln : kln;
    float lw[4];
    #pragma unroll
    for (int ct = 0; ct < 4; ++ct) lw[ct] = ln[ct * 16 + lm];

    bf16* base = (kind == 0) ? qo + ((size_t)(b * 12 + head) * 2048 + s0) * 64
                             : ko + ((size_t)(b * 4  + head) * 2048 + s0) * 64;
    #pragma unroll
    for (int r = 0; r < 4; ++r) {
        float n0 = acc[0][r], n1 = acc[1][r], n2 = acc[2][r], n3 = acc[3][r];
        float ss = n0 * n0 + n1 * n1 + n2 * n2 + n3 * n3;
        ss += __shfl_xor(ss, 1);
        ss += __shfl_xor(ss, 2);
        ss += __shfl_xor(ss, 4);
        ss += __shfl_xor(ss, 8);
        float rms = rsqrtf(ss * (1.0f / 64.0f) + 1e-6f);
        n0 *= rms * lw[0]; n1 *= rms * lw[1]; n2 *= rms * lw[2]; n3 *= rms * lw[3];
        const int row = w * 16 + lg * 4 + r;
        const float2* tp = tab + (size_t)(s0 + row) * 32;
        float2 t0 = tp[lm], t1 = tp[lm + 16];
        bf16* dst = base + (size_t)row * 64;
        dst[lm]      = __float2bfloat16(n0 * t0.x - n2 * t0.y);
        dst[lm + 16] = __float2bfloat16(n1 * t1.x - n3 * t1.y);
        dst[lm + 32] = __float2bfloat16(n2 * t0.x + n0 * t0.y);
        dst[lm + 48] = __float2bfloat16(n3 * t1.x + n1 * t1.y);
    }
}

// ================= Kernel 2: MFMA sliding-window attention =================
// grid (32 q-tiles, 12 heads, 2 batch); 4 waves/block, wave w owns q-rows [16w,16w+16)
__global__ __launch_bounds__(256) void k_attn(
    const bf16* __restrict__ qi, const bf16* __restrict__ ki,
    const bf16* __restrict__ vti, bf16* __restrict__ ao)
{
    __shared__ bf16 Ks[64 * 72];   // [key][d]
    __shared__ bf16 Vs[64 * 72];   // [d][key]
    __shared__ bf16 Ps[64 * 72];   // [q][key], per-wave-private rows
    const int tid = threadIdx.x;
    const int w = tid >> 6, l = tid & 63;
    const int lm = l & 15, lg = l >> 4;
    const int qb = blockIdx.x, h = blockIdx.y, b = blockIdx.z;
    const int kv = h / 3;
    const int q0 = qb * 64;

    const bf16* qbase = qi + ((size_t)((b * 12 + h) * 2048 + q0 + w * 16 + lm)) * 64 + lg * 8;
    bf16x8 qf0 = *(const bf16x8*)(qbase);
    bf16x8 qf1 = *(const bf16x8*)(qbase + 32);

    f32x4 oacc[4] = {};
    float m_[4], l_[4];
    #pragma unroll
    for (int r = 0; r < 4; ++r) { m_[r] = -INFINITY; l_[r] = 0.f; }

    const int sr = tid >> 2, sc = (tid & 3) * 16;
    const bf16* kgb = ki  + (size_t)(b * 4 + kv) * 2048 * 64;
    const bf16* vgb = vti + (size_t)(b * 4 + kv) * 64 * 2048;

    const int kb_lo = (qb > 6) ? (qb - 6) : 0;
    for (int kb = kb_lo; kb <= qb; ++kb) {
        const int k0 = kb * 64;
        __syncthreads();
        {
            const bf16* kp = kgb + (size_t)(k0 + sr) * 64 + sc;
            bf16x8 t0 = *(const bf16x8*)(kp);
            bf16x8 t1 = *(const bf16x8*)(kp + 8);
            const bf16* vp = vgb + (size_t)sr * 2048 + k0 + sc;
            bf16x8 t2 = *(const bf16x8*)(vp);
            bf16x8 t3 = *(const bf16x8*)(vp + 8);
            *(bf16x8*)(&Ks[sr * 72 + sc])     = t0;
            *(bf16x8*)(&Ks[sr * 72 + sc + 8]) = t1;
            *(bf16x8*)(&Vs[sr * 72 + sc])     = t2;
            *(bf16x8*)(&Vs[sr * 72 + sc + 8]) = t3;
        }
        __syncthreads();

        f32x4 sacc[4];
        #pragma unroll
        for (int kt = 0; kt < 4; ++kt) {
            bf16x8 kf0 = *(const bf16x8*)(&Ks[(kt * 16 + lm) * 72 + lg * 8]);
            bf16x8 kf1 = *(const bf16x8*)(&Ks[(kt * 16 + lm) * 72 + 32 + lg * 8]);
            f32x4 z = {0.f, 0.f, 0.f, 0.f};
            z = MFMA16(qf0, kf0, z);
            sacc[kt] = MFMA16(qf1, kf1, z);
        }

        float pmax[4] = {-INFINITY, -INFINITY, -INFINITY, -INFINITY};
        #pragma unroll
        for (int kt = 0; kt < 4; ++kt)
            #pragma unroll
            for (int r = 0; r < 4; ++r) {
                int kgl = k0 + kt * 16 + lm;
                int qgl = q0 + w * 16 + lg * 4 + r;
                bool ok = (kgl <= qgl) && (kgl > qgl - 384);
                float s = ok ? sacc[kt][r] * 0.125f : -INFINITY;
                sacc[kt][r] = s;
                pmax[r] = fmaxf(pmax[r], s);
            }
        #pragma unroll
        for (int r = 0; r < 4; ++r) {
            float t = pmax[r];
            t = fmaxf(t, __shfl_xor(t, 1));
            t = fmaxf(t, __shfl_xor(t, 2));
            t = fmaxf(t, __shfl_xor(t, 4));
            t = fmaxf(t, __shfl_xor(t, 8));
            pmax[r] = t;
        }

        #pragma unroll
        for (int r = 0; r < 4; ++r) {
            float mnew = fmaxf(m_[r], pmax[r]);
            float scale, rs = 0.f, p[4];
            if (mnew > -INFINITY) {
                scale = expf(m_[r] - mnew);
                #pragma unroll
                for (int kt = 0; kt < 4; ++kt) { p[kt] = expf(sacc[kt][r] - mnew); rs += p[kt]; }
            } else {
                scale = 1.f;
                #pragma unroll
                for (int kt = 0; kt < 4; ++kt) p[kt] = 0.f;
            }
            m_[r] = mnew;
            rs += __shfl_xor(rs, 1);
            rs += __shfl_xor(rs, 2);
            rs += __shfl_xor(rs, 4);
            rs += __shfl_xor(rs, 8);
            l_[r] = l_[r] * scale + rs;
            #pragma unroll
            for (int dt = 0; dt < 4; ++dt) oacc[dt][r] *= scale;
            #pragma unroll
            for (int kt = 0; kt < 4; ++kt)
                Ps[(w * 16 + lg * 4 + r) * 72 + kt * 16 + lm] = __float2bfloat16(p[kt]);
        }

        bf16x8 pf0 = *(const bf16x8*)(&Ps[(w * 16 + lm) * 72 + lg * 8]);
        bf16x8 pf1 = *(const bf16x8*)(&Ps[(w * 16 + lm) * 72 + 32 + lg * 8]);
        #pragma unroll
        for (int dt = 0; dt < 4; ++dt) {
            bf16x8 vf0 = *(const bf16x8*)(&Vs[(dt * 16 + lm) * 72 + lg * 8]);
            bf16x8 vf1 = *(const bf16x8*)(&Vs[(dt * 16 + lm) * 72 + 32 + lg * 8]);
            oacc[dt] = MFMA16(pf0, vf0, oacc[dt]);
            oacc[dt] = MFMA16(pf1, vf1, oacc[dt]);
        }
    }

    #pragma unroll
    for (int r = 0; r < 4; ++r) {
        float inv = 1.f / l_[r];
        bf16* dst = ao + ((size_t)(b * 2048 + q0 + w * 16 + lg * 4 + r)) * 768 + h * 64;
        #pragma unroll
        for (int dt = 0; dt < 4; ++dt)
            dst[dt * 16 + lm] = __float2bfloat16(oacc[dt][r] * inv);
    }
}

// ================= Kernel 3: MFMA output projection =================
// A: bf16 [4096][768], W: fp32 [768][768], out fp32. grid (64 m, 12 n), 4 waves.
__global__ __launch_bounds__(256) void k_oproj(
    const bf16* __restrict__ A, const float* __restrict__ W, float* __restrict__ out)
{
    __shared__ bf16 As[64 * 72];
    __shared__ bf16 Bs[64 * 72];
    const int tid = threadIdx.x;
    const int w = tid >> 6, l = tid & 63;
    const int lm = l & 15, lg = l >> 4;
    const int m0 = blockIdx.x * 64, n0 = blockIdx.y * 64;

    const int sr = tid >> 2, lk = (tid & 3) * 4;  // fp32 staging cols
    const int ca = (tid & 3) * 8;                 // bf16 staging cols
    const bf16*  aptr = A + (size_t)(m0 + sr) * 768 + ca;
    const float* bptr = W + (size_t)(n0 + sr) * 768 + lk;

    f32x4 acc[4] = {};

    for (int k0 = 0; k0 < 768; k0 += 64) {
        bf16x8 a0 = *(const bf16x8*)(aptr + k0);
        bf16x8 a1 = *(const bf16x8*)(aptr + k0 + 32);
        float4 fb[4];
        #pragma unroll
        for (int i = 0; i < 4; ++i) fb[i] = *reinterpret_cast<const float4*>(bptr + k0 + 16 * i);
        __syncthreads();
        *(bf16x8*)(&As[sr * 72 + ca])      = a0;
        *(bf16x8*)(&As[sr * 72 + ca + 32]) = a1;
        #pragma unroll
        for (int i = 0; i < 4; ++i) st4bf(&Bs[sr * 72 + lk + 16 * i], fb[i]);
        __syncthreads();
        #pragma unroll
        for (int kk = 0; kk < 2; ++kk) {
            bf16x8 af = *(const bf16x8*)(&As[(w * 16 + lm) * 72 + kk * 32 + lg * 8]);
            #pragma unroll
            for (int ct = 0; ct < 4; ++ct) {
                bf16x8 bfr = *(const bf16x8*)(&Bs[(ct * 16 + lm) * 72 + kk * 32 + lg * 8]);
                acc[ct] = MFMA16(af, bfr, acc[ct]);
            }
        }
    }

    #pragma unroll
    for (int r = 0; r < 4; ++r) {
        float* dst = out + (size_t)(m0 + w * 16 + lg * 4 + r) * 768 + n0;
        #pragma unroll
        for (int ct = 0; ct < 4; ++ct)
            dst[ct * 16 + lm] = acc[ct][r];
    }
}

extern "C" void kernel_launch(void* const* d_in, const int* in_sizes, int n_in,
                              void* d_out, int out_size, void* d_ws, size_t ws_size,
                              hipStream_t stream) {
    const float* hs  = (const float*)d_in[0];
    const float* qw  = (const float*)d_in[1];
    const float* kw  = (const float*)d_in[2];
    const float* vw  = (const float*)d_in[3];
    const float* ow  = (const float*)d_in[4];
    const float* qln = (const float*)d_in[5];
    const float* kln = (const float*)d_in[6];
    float* out = (float*)d_out;

    // ws: tab float2[65536] (512KB) | bf16: q[3145728] k[1048576] vT[1048576] attn[3145728]
    float2* tab = (float2*)d_ws;
    bf16* q_ws  = (bf16*)(tab + 65536);
    bf16* k_ws  = q_ws + 3145728;
    bf16* vt_ws = k_ws + 1048576;
    bf16* a_ws  = vt_ws + 1048576;

    k_tab<<<dim3(256), 256, 0, stream>>>(tab);
    k_qkv<<<dim3(64, 20, 1), 256, 0, stream>>>(hs, qw, kw, vw, qln, kln, tab, q_ws, k_ws, vt_ws);
    k_attn<<<dim3(32, 12, 2), 256, 0, stream>>>(q_ws, k_ws, vt_ws, a_ws);
    k_oproj<<<dim3(64, 12, 1), 256, 0, stream>>>(a_ws, ow, out);
}

// Round 5
// 73.746 us; speedup vs baseline: 6.6636x; 1.1251x over previous
//
#include <hip/hip_runtime.h>
#include <hip/hip_bf16.h>

typedef __hip_bfloat16 bf16;
typedef __attribute__((ext_vector_type(8))) short bf16x8;   // 8 bf16 = 4 VGPR
typedef __attribute__((ext_vector_type(4))) float f32x4;

#define MFMA16(a, b, c) __builtin_amdgcn_mfma_f32_16x16x32_bf16((a), (b), (c), 0, 0, 0)

// ---- constants ----
// B=2, S=2048, D=768, HD=64, NH=12, NKV=4, GROUPS=3, WINDOW=384, theta=1e4, eps=1e-6
// I/O fp32; bf16 intermediates in ws; V stored transposed [b][kv][d][s].

__device__ __forceinline__ void st4bf(bf16* p, float4 v) {
    bf16 t[4];
    t[0] = __float2bfloat16(v.x); t[1] = __float2bfloat16(v.y);
    t[2] = __float2bfloat16(v.z); t[3] = __float2bfloat16(v.w);
    *reinterpret_cast<uint2*>(p) = *reinterpret_cast<const uint2*>(t);
}

// ============ Kernel 0: fp32->bf16 conversion of hs + weights, and RoPE table ======
// blocks: [0,3072) hs | [3072,3648) qw | [3648,3840) kw | [3840,4032) vw | [4032,4608) ow
// [4608,4864): cos/sin table, tab[s*32+f] = (cos, sin)(s * theta^(-f/32))
__global__ __launch_bounds__(256) void k_prep(
    const float* __restrict__ hs, const float* __restrict__ qw,
    const float* __restrict__ kw, const float* __restrict__ vw,
    const float* __restrict__ ow,
    bf16* __restrict__ hsb, bf16* __restrict__ qwb, bf16* __restrict__ kwb,
    bf16* __restrict__ vwb, bf16* __restrict__ owb, float2* __restrict__ tab)
{
    const int bid = blockIdx.x, tid = threadIdx.x;
    const float* src; bf16* dst; int rel;
    if (bid < 3072)      { src = hs; dst = hsb; rel = bid; }
    else if (bid < 3648) { src = qw; dst = qwb; rel = bid - 3072; }
    else if (bid < 3840) { src = kw; dst = kwb; rel = bid - 3648; }
    else if (bid < 4032) { src = vw; dst = vwb; rel = bid - 3840; }
    else if (bid < 4608) { src = ow; dst = owb; rel = bid - 4032; }
    else {
        int i = (bid - 4608) * 256 + tid;          // 65536 entries
        int f = i & 31;
        float ang = (float)(i >> 5) * expf(-(float)f * 0.28782313662425572f);  // ln(1e4)/32
        float sn, cs; sincosf(ang, &sn, &cs);
        tab[i] = make_float2(cs, sn);
        return;
    }
    int i = (rel * 256 + tid) * 4;
    float4 v = *reinterpret_cast<const float4*>(src + i);
    st4bf(dst + i, v);
}

// ================= Kernel 1: MFMA QKV GEMM + RMSNorm + RoPE (bf16 in) ============
// grid (64 m-tiles, 20 n-blocks): 0-11 q heads, 12-15 k heads, 16-19 v heads.
__global__ __launch_bounds__(256) void k_qkv(
    const bf16* __restrict__ hsb, const bf16* __restrict__ qwb,
    const bf16* __restrict__ kwb, const bf16* __restrict__ vwb,
    const float* __restrict__ qln, const float* __restrict__ kln,
    const float2* __restrict__ tab,
    bf16* __restrict__ qo, bf16* __restrict__ ko, bf16* __restrict__ vto)
{
    __shared__ bf16 As[2][64 * 72];
    __shared__ bf16 Bs[2][64 * 72];
    const int tid = threadIdx.x;
    const int w = tid >> 6, l = tid & 63;
    const int lm = l & 15, lg = l >> 4;
    const int m0 = blockIdx.x * 64;
    const int nblk = blockIdx.y;

    const bf16* wsrc; int wrow0, kind, head;
    if (nblk < 12)      { wsrc = qwb; wrow0 = nblk * 64;        kind = 0; head = nblk; }
    else if (nblk < 16) { wsrc = kwb; wrow0 = (nblk - 12) * 64; kind = 1; head = nblk - 12; }
    else                { wsrc = vwb; wrow0 = (nblk - 16) * 64; kind = 2; head = nblk - 16; }

    const int sr = tid >> 2, sc = (tid & 3) * 16;
    const bf16* aptr = hsb  + (size_t)(m0 + sr) * 768 + sc;
    const bf16* bptr = wsrc + (size_t)(wrow0 + sr) * 768 + sc;

    // prologue: tile 0 -> buf 0
    bf16x8 ra0 = *(const bf16x8*)(aptr);
    bf16x8 ra1 = *(const bf16x8*)(aptr + 8);
    bf16x8 rb0 = *(const bf16x8*)(bptr);
    bf16x8 rb1 = *(const bf16x8*)(bptr + 8);
    *(bf16x8*)(&As[0][sr * 72 + sc])     = ra0;
    *(bf16x8*)(&As[0][sr * 72 + sc + 8]) = ra1;
    *(bf16x8*)(&Bs[0][sr * 72 + sc])     = rb0;
    *(bf16x8*)(&Bs[0][sr * 72 + sc + 8]) = rb1;
    __syncthreads();

    f32x4 acc[4] = {};
    for (int t = 0; t < 12; ++t) {
        const int p = t & 1;
        if (t < 11) {   // issue next-tile loads before compute (latency hides under MFMA)
            const bf16* ap = aptr + (t + 1) * 64;
            const bf16* bp = bptr + (t + 1) * 64;
            ra0 = *(const bf16x8*)(ap);
            ra1 = *(const bf16x8*)(ap + 8);
            rb0 = *(const bf16x8*)(bp);
            rb1 = *(const bf16x8*)(bp + 8);
        }
        #pragma unroll
        for (int kk = 0; kk < 2; ++kk) {
            bf16x8 af = *(const bf16x8*)(&As[p][(w * 16 + lm) * 72 + kk * 32 + lg * 8]);
            #pragma unroll
            for (int ct = 0; ct < 4; ++ct) {
                bf16x8 bfr = *(const bf16x8*)(&Bs[p][(ct * 16 + lm) * 72 + kk * 32 + lg * 8]);
                acc[ct] = MFMA16(af, bfr, acc[ct]);
            }
        }
        if (t < 11) {
            __syncthreads();
            *(bf16x8*)(&As[p ^ 1][sr * 72 + sc])     = ra0;
            *(bf16x8*)(&As[p ^ 1][sr * 72 + sc + 8]) = ra1;
            *(bf16x8*)(&Bs[p ^ 1][sr * 72 + sc])     = rb0;
            *(bf16x8*)(&Bs[p ^ 1][sr * 72 + sc + 8]) = rb1;
            __syncthreads();
        }
    }

    const int b  = m0 >> 11;
    const int s0 = m0 & 2047;

    if (kind == 2) {  // V: write TRANSPOSED [b][kv][d][s]
        bf16* base = vto + (size_t)(b * 4 + head) * 64 * 2048;
        #pragma unroll
        for (int r = 0; r < 4; ++r) {
            const int s = s0 + w * 16 + lg * 4 + r;
            #pragma unroll
            for (int ct = 0; ct < 4; ++ct)
                base[(size_t)(ct * 16 + lm) * 2048 + s] = __float2bfloat16(acc[ct][r]);
        }
        return;
    }

    const float* ln = (kind == 0) ? qln : kln;
    float lw[4];
    #pragma unroll
    for (int ct = 0; ct < 4; ++ct) lw[ct] = ln[ct * 16 + lm];

    bf16* base = (kind == 0) ? qo + ((size_t)(b * 12 + head) * 2048 + s0) * 64
                             : ko + ((size_t)(b * 4  + head) * 2048 + s0) * 64;
    #pragma unroll
    for (int r = 0; r < 4; ++r) {
        float n0 = acc[0][r], n1 = acc[1][r], n2 = acc[2][r], n3 = acc[3][r];
        float ss = n0 * n0 + n1 * n1 + n2 * n2 + n3 * n3;
        ss += __shfl_xor(ss, 1);
        ss += __shfl_xor(ss, 2);
        ss += __shfl_xor(ss, 4);
        ss += __shfl_xor(ss, 8);
        float rms = rsqrtf(ss * (1.0f / 64.0f) + 1e-6f);
        n0 *= rms * lw[0]; n1 *= rms * lw[1]; n2 *= rms * lw[2]; n3 *= rms * lw[3];
        const int row = w * 16 + lg * 4 + r;
        const float2* tp = tab + (size_t)(s0 + row) * 32;
        float2 t0 = tp[lm], t1 = tp[lm + 16];
        bf16* dst = base + (size_t)row * 64;
        dst[lm]      = __float2bfloat16(n0 * t0.x - n2 * t0.y);
        dst[lm + 16] = __float2bfloat16(n1 * t1.x - n3 * t1.y);
        dst[lm + 32] = __float2bfloat16(n2 * t0.x + n0 * t0.y);
        dst[lm + 48] = __float2bfloat16(n3 * t1.x + n1 * t1.y);
    }
}

// ================= Kernel 2: MFMA sliding-window attention (dbuf K/V) ============
__global__ __launch_bounds__(256) void k_attn(
    const bf16* __restrict__ qi, const bf16* __restrict__ ki,
    const bf16* __restrict__ vti, bf16* __restrict__ ao)
{
    __shared__ bf16 Ks[2][64 * 72];   // [key][d]
    __shared__ bf16 Vs[2][64 * 72];   // [d][key]
    __shared__ bf16 Ps[64 * 72];      // per-wave-private rows
    const int tid = threadIdx.x;
    const int w = tid >> 6, l = tid & 63;
    const int lm = l & 15, lg = l >> 4;
    const int qb = blockIdx.x, h = blockIdx.y, b = blockIdx.z;
    const int kv = h / 3;
    const int q0 = qb * 64;

    const bf16* qbase = qi + ((size_t)((b * 12 + h) * 2048 + q0 + w * 16 + lm)) * 64 + lg * 8;
    bf16x8 qf0 = *(const bf16x8*)(qbase);
    bf16x8 qf1 = *(const bf16x8*)(qbase + 32);

    f32x4 oacc[4] = {};
    float m_[4], l_[4];
    #pragma unroll
    for (int r = 0; r < 4; ++r) { m_[r] = -INFINITY; l_[r] = 0.f; }

    const int sr = tid >> 2, sc = (tid & 3) * 16;
    const bf16* kgb = ki  + (size_t)(b * 4 + kv) * 2048 * 64;
    const bf16* vgb = vti + (size_t)(b * 4 + kv) * 64 * 2048;

    const int kb_lo = (qb > 6) ? (qb - 6) : 0;
    {   // prologue: stage tile kb_lo -> buf 0
        const bf16* kp = kgb + (size_t)(kb_lo * 64 + sr) * 64 + sc;
        const bf16* vp = vgb + (size_t)sr * 2048 + kb_lo * 64 + sc;
        *(bf16x8*)(&Ks[0][sr * 72 + sc])     = *(const bf16x8*)(kp);
        *(bf16x8*)(&Ks[0][sr * 72 + sc + 8]) = *(const bf16x8*)(kp + 8);
        *(bf16x8*)(&Vs[0][sr * 72 + sc])     = *(const bf16x8*)(vp);
        *(bf16x8*)(&Vs[0][sr * 72 + sc + 8]) = *(const bf16x8*)(vp + 8);
    }
    __syncthreads();

    for (int kb = kb_lo; kb <= qb; ++kb) {
        const int p = (kb - kb_lo) & 1;
        const int k0 = kb * 64;

        bf16x8 rk0, rk1, rv0, rv1;
        if (kb < qb) {   // prefetch next K/V tile
            const bf16* kp = kgb + (size_t)(k0 + 64 + sr) * 64 + sc;
            const bf16* vp = vgb + (size_t)sr * 2048 + k0 + 64 + sc;
            rk0 = *(const bf16x8*)(kp);
            rk1 = *(const bf16x8*)(kp + 8);
            rv0 = *(const bf16x8*)(vp);
            rv1 = *(const bf16x8*)(vp + 8);
        }

        f32x4 sacc[4];
        #pragma unroll
        for (int kt = 0; kt < 4; ++kt) {
            bf16x8 kf0 = *(const bf16x8*)(&Ks[p][(kt * 16 + lm) * 72 + lg * 8]);
            bf16x8 kf1 = *(const bf16x8*)(&Ks[p][(kt * 16 + lm) * 72 + 32 + lg * 8]);
            f32x4 z = {0.f, 0.f, 0.f, 0.f};
            z = MFMA16(qf0, kf0, z);
            sacc[kt] = MFMA16(qf1, kf1, z);
        }

        float pmax[4] = {-INFINITY, -INFINITY, -INFINITY, -INFINITY};
        #pragma unroll
        for (int kt = 0; kt < 4; ++kt)
            #pragma unroll
            for (int r = 0; r < 4; ++r) {
                int kgl = k0 + kt * 16 + lm;
                int qgl = q0 + w * 16 + lg * 4 + r;
                bool ok = (kgl <= qgl) && (kgl > qgl - 384);
                float s = ok ? sacc[kt][r] * 0.125f : -INFINITY;
                sacc[kt][r] = s;
                pmax[r] = fmaxf(pmax[r], s);
            }
        #pragma unroll
        for (int r = 0; r < 4; ++r) {
            float t = pmax[r];
            t = fmaxf(t, __shfl_xor(t, 1));
            t = fmaxf(t, __shfl_xor(t, 2));
            t = fmaxf(t, __shfl_xor(t, 4));
            t = fmaxf(t, __shfl_xor(t, 8));
            pmax[r] = t;
        }

        #pragma unroll
        for (int r = 0; r < 4; ++r) {
            float mnew = fmaxf(m_[r], pmax[r]);
            float scale, rs = 0.f, pv[4];
            if (mnew > -INFINITY) {
                scale = expf(m_[r] - mnew);
                #pragma unroll
                for (int kt = 0; kt < 4; ++kt) { pv[kt] = expf(sacc[kt][r] - mnew); rs += pv[kt]; }
            } else {
                scale = 1.f;
                #pragma unroll
                for (int kt = 0; kt < 4; ++kt) pv[kt] = 0.f;
            }
            m_[r] = mnew;
            rs += __shfl_xor(rs, 1);
            rs += __shfl_xor(rs, 2);
            rs += __shfl_xor(rs, 4);
            rs += __shfl_xor(rs, 8);
            l_[r] = l_[r] * scale + rs;
            #pragma unroll
            for (int dt = 0; dt < 4; ++dt) oacc[dt][r] *= scale;
            #pragma unroll
            for (int kt = 0; kt < 4; ++kt)
                Ps[(w * 16 + lg * 4 + r) * 72 + kt * 16 + lm] = __float2bfloat16(pv[kt]);
        }

        bf16x8 pf0 = *(const bf16x8*)(&Ps[(w * 16 + lm) * 72 + lg * 8]);
        bf16x8 pf1 = *(const bf16x8*)(&Ps[(w * 16 + lm) * 72 + 32 + lg * 8]);
        #pragma unroll
        for (int dt = 0; dt < 4; ++dt) {
            bf16x8 vf0 = *(const bf16x8*)(&Vs[p][(dt * 16 + lm) * 72 + lg * 8]);
            bf16x8 vf1 = *(const bf16x8*)(&Vs[p][(dt * 16 + lm) * 72 + 32 + lg * 8]);
            oacc[dt] = MFMA16(pf0, vf0, oacc[dt]);
            oacc[dt] = MFMA16(pf1, vf1, oacc[dt]);
        }

        if (kb < qb) {
            __syncthreads();
            *(bf16x8*)(&Ks[p ^ 1][sr * 72 + sc])     = rk0;
            *(bf16x8*)(&Ks[p ^ 1][sr * 72 + sc + 8]) = rk1;
            *(bf16x8*)(&Vs[p ^ 1][sr * 72 + sc])     = rv0;
            *(bf16x8*)(&Vs[p ^ 1][sr * 72 + sc + 8]) = rv1;
            __syncthreads();
        }
    }

    #pragma unroll
    for (int r = 0; r < 4; ++r) {
        float inv = 1.f / l_[r];
        bf16* dst = ao + ((size_t)(b * 2048 + q0 + w * 16 + lg * 4 + r)) * 768 + h * 64;
        #pragma unroll
        for (int dt = 0; dt < 4; ++dt)
            dst[dt * 16 + lm] = __float2bfloat16(oacc[dt][r] * inv);
    }
}

// ================= Kernel 3: MFMA output projection (bf16 in, fp32 out) ==========
__global__ __launch_bounds__(256) void k_oproj(
    const bf16* __restrict__ A, const bf16* __restrict__ W, float* __restrict__ out)
{
    __shared__ bf16 As[2][64 * 72];
    __shared__ bf16 Bs[2][64 * 72];
    const int tid = threadIdx.x;
    const int w = tid >> 6, l = tid & 63;
    const int lm = l & 15, lg = l >> 4;
    const int m0 = blockIdx.x * 64, n0 = blockIdx.y * 64;

    const int sr = tid >> 2, sc = (tid & 3) * 16;
    const bf16* aptr = A + (size_t)(m0 + sr) * 768 + sc;
    const bf16* bptr = W + (size_t)(n0 + sr) * 768 + sc;

    bf16x8 ra0 = *(const bf16x8*)(aptr);
    bf16x8 ra1 = *(const bf16x8*)(aptr + 8);
    bf16x8 rb0 = *(const bf16x8*)(bptr);
    bf16x8 rb1 = *(const bf16x8*)(bptr + 8);
    *(bf16x8*)(&As[0][sr * 72 + sc])     = ra0;
    *(bf16x8*)(&As[0][sr * 72 + sc + 8]) = ra1;
    *(bf16x8*)(&Bs[0][sr * 72 + sc])     = rb0;
    *(bf16x8*)(&Bs[0][sr * 72 + sc + 8]) = rb1;
    __syncthreads();

    f32x4 acc[4] = {};
    for (int t = 0; t < 12; ++t) {
        const int p = t & 1;
        if (t < 11) {
            const bf16* ap = aptr + (t + 1) * 64;
            const bf16* bp = bptr + (t + 1) * 64;
            ra0 = *(const bf16x8*)(ap);
            ra1 = *(const bf16x8*)(ap + 8);
            rb0 = *(const bf16x8*)(bp);
            rb1 = *(const bf16x8*)(bp + 8);
        }
        #pragma unroll
        for (int kk = 0; kk < 2; ++kk) {
            bf16x8 af = *(const bf16x8*)(&As[p][(w * 16 + lm) * 72 + kk * 32 + lg * 8]);
            #pragma unroll
            for (int ct = 0; ct < 4; ++ct) {
                bf16x8 bfr = *(const bf16x8*)(&Bs[p][(ct * 16 + lm) * 72 + kk * 32 + lg * 8]);
                acc[ct] = MFMA16(af, bfr, acc[ct]);
            }
        }
        if (t < 11) {
            __syncthreads();
            *(bf16x8*)(&As[p ^ 1][sr * 72 + sc])     = ra0;
            *(bf16x8*)(&As[p ^ 1][sr * 72 + sc + 8]) = ra1;
            *(bf16x8*)(&Bs[p ^ 1][sr * 72 + sc])     = rb0;
            *(bf16x8*)(&Bs[p ^ 1][sr * 72 + sc + 8]) = rb1;
            __syncthreads();
        }
    }

    #pragma unroll
    for (int r = 0; r < 4; ++r) {
        float* dst = out + (size_t)(m0 + w * 16 + lg * 4 + r) * 768 + n0;
        #pragma unroll
        for (int ct = 0; ct < 4; ++ct)
            dst[ct * 16 + lm] = acc[ct][r];
    }
}

extern "C" void kernel_launch(void* const* d_in, const int* in_sizes, int n_in,
                              void* d_out, int out_size, void* d_ws, size_t ws_size,
                              hipStream_t stream) {
    const float* hs  = (const float*)d_in[0];
    const float* qw  = (const float*)d_in[1];
    const float* kw  = (const float*)d_in[2];
    const float* vw  = (const float*)d_in[3];
    const float* ow  = (const float*)d_in[4];
    const float* qln = (const float*)d_in[5];
    const float* kln = (const float*)d_in[6];
    float* out = (float*)d_out;

    // ws layout (20.4 MB of ~256 MB):
    // tab | q_ws | k_ws | vt_ws | X (hsb then attn-out) | qwb | kwb | vwb | owb
    float2* tab  = (float2*)d_ws;
    bf16*   q_ws = (bf16*)(tab + 65536);
    bf16*   k_ws = q_ws + 3145728;
    bf16*   vt_ws= k_ws + 1048576;
    bf16*   x_ws = vt_ws + 1048576;    // 3145728: hsb during k_qkv, attn output after
    bf16*   qwb  = x_ws + 3145728;
    bf16*   kwb  = qwb + 589824;
    bf16*   vwb  = kwb + 196608;
    bf16*   owb  = vwb + 196608;

    k_prep<<<dim3(4864), 256, 0, stream>>>(hs, qw, kw, vw, ow, x_ws, qwb, kwb, vwb, owb, tab);
    k_qkv<<<dim3(64, 20, 1), 256, 0, stream>>>(x_ws, qwb, kwb, vwb, qln, kln, tab, q_ws, k_ws, vt_ws);
    k_attn<<<dim3(32, 12, 2), 256, 0, stream>>>(q_ws, k_ws, vt_ws, x_ws);
    k_oproj<<<dim3(64, 12, 1), 256, 0, stream>>>(x_ws, owb, out);
}